// Round 5
// baseline (702.790 us; speedup 1.0000x reference)
//
#include <hip/hip_runtime.h>
#include <hip/hip_bf16.h>

typedef __hip_bfloat16 bf16;
typedef __attribute__((ext_vector_type(4))) float floatx4;
typedef __attribute__((ext_vector_type(8))) short shortx8;

#define MFMA16(a, b, c) __builtin_amdgcn_mfma_f32_16x16x32_bf16(a, b, c, 0, 0, 0)

// async global->LDS, 16 B per lane. LDS dest is wave-uniform base + lane*16.
__device__ __forceinline__ void gll16(const bf16* g, void* l) {
  __builtin_amdgcn_global_load_lds((const __attribute__((address_space(1))) unsigned int*)g,
                                   (__attribute__((address_space(3))) unsigned int*)l,
                                   16, 0, 0);
}

// ---------------------------------------------------------------------------
// fused fp32 -> bf16 converts: src (16384 blks) + 6 weights (8192 blks)
// ---------------------------------------------------------------------------
__global__ __launch_bounds__(256) void f2b_all(
    const float* __restrict__ src, const float* __restrict__ Wq,
    const float* __restrict__ Wk, const float* __restrict__ Wv,
    const float* __restrict__ Wo, const float* __restrict__ W1,
    const float* __restrict__ W2, bf16* __restrict__ src_bf,
    bf16* __restrict__ Wq_b, bf16* __restrict__ Wk_b, bf16* __restrict__ Wv_b,
    bf16* __restrict__ Wo_b, bf16* __restrict__ W1_b, bf16* __restrict__ W2_b) {
  const int blk = blockIdx.x;
  const float* in;
  bf16* out;
  int off;
  if (blk < 16384)      { in = src; out = src_bf; off = blk; }
  else if (blk < 17408) { in = Wq; out = Wq_b; off = blk - 16384; }
  else if (blk < 18432) { in = Wk; out = Wk_b; off = blk - 17408; }
  else if (blk < 19456) { in = Wv; out = Wv_b; off = blk - 18432; }
  else if (blk < 20480) { in = Wo; out = Wo_b; off = blk - 19456; }
  else if (blk < 22528) { in = W1; out = W1_b; off = blk - 20480; }
  else                  { in = W2; out = W2_b; off = blk - 22528; }
  const int i = (off * 256 + threadIdx.x) * 4;
  float4 v = *(const float4*)(in + i);
  bf16 h0 = __float2bfloat16(v.x), h1 = __float2bfloat16(v.y);
  bf16 h2 = __float2bfloat16(v.z), h3 = __float2bfloat16(v.w);
  ushort4 u;
  u.x = __builtin_bit_cast(unsigned short, h0);
  u.y = __builtin_bit_cast(unsigned short, h1);
  u.z = __builtin_bit_cast(unsigned short, h2);
  u.w = __builtin_bit_cast(unsigned short, h3);
  *(ushort4*)(out + i) = u;
}

// ---------------------------------------------------------------------------
// NT GEMM: C[n,m] = A[n,:] . W[m,:]  (A [N,K] bf16, W [M,K] bf16, K-major)
// Tile 128(M-rows of A) x 256(N-cols = W rows), BK=32, 24 KB LDS, 256 thr.
// 4 waves (2x2), each wave 64x128 via 4x8 of 16x16x32 MFMA.
// WHY 128x256: round-2..4 PMC shows the GEMMs are limited by global->LDS
// staging DELIVERY (~8 TB/s aggregate) serialized with compute at the
// barrier: dispatch time ~= M*N*K*2*(1/BM+1/BN) / 8TB/s. BK and bank
// conflicts were proven neutral; staged-bytes-per-FLOP is the lever.
// XOR-4 swizzle on the global-fetch side (round-3: conflicts 8.4M -> 0):
// chunk position p of row r holds global chunk p^((r>>1)&3).
// EPI: 1 = identity -> bf16 ; 2 = relu -> bf16 ; 3 = + residual(fp32) -> fp32
//      4 = fused QKV: col-range selects phi->phiQ / phi->phiK / id->V
// ---------------------------------------------------------------------------
template <int EPI>
__global__ __launch_bounds__(256, 2) void gemm_nt(
    const bf16* __restrict__ A, const bf16* __restrict__ Bw,
    const float* __restrict__ bias0, const float* __restrict__ bias1,
    const float* __restrict__ bias2, const float* __restrict__ res,
    void* __restrict__ out0, void* __restrict__ out1, void* __restrict__ out2,
    const int M, const int K) {
  __shared__ __align__(16) bf16 sA[128][32];
  __shared__ __align__(16) bf16 sB[256][32];
  const int tid = threadIdx.x;
  const int lane = tid & 63, wave = tid >> 6;
  const int wm = wave & 1, wn = wave >> 1;
  const int bm = blockIdx.x, bn = blockIdx.y;
  floatx4 acc[4][8] = {};
  // staging: each gll call covers 64 rows; lane -> row tid>>2, chunk pos tid&3
  // which receives global chunk (tid&3)^((row>>1)&3)
  const int srow = tid >> 2;
  const int schunk = (tid & 3) ^ ((srow >> 1) & 3);
  const bf16* Ab = A + (size_t)(bm * 128 + srow) * K + schunk * 8;
  const bf16* Bb = Bw + (size_t)(bn * 256 + srow) * K + schunk * 8;
  char* sAc = (char*)sA;
  char* sBc = (char*)sB;
  const int woff = wave * 1024;  // wave-uniform slab within each 4KB call-block
  const int frow = lane & 15;
  const int fks = (((lane >> 4) ^ ((frow >> 1) & 3))) << 3;  // swizzled chunk
  const size_t rK = (size_t)64 * K;

  for (int k0 = 0; k0 < K; k0 += 32) {
    __syncthreads();  // previous tile fully consumed
    gll16(Ab + k0, sAc + woff);
    gll16(Ab + rK + k0, sAc + 4096 + woff);
    gll16(Bb + k0, sBc + woff);
    gll16(Bb + rK + k0, sBc + 4096 + woff);
    gll16(Bb + 2 * rK + k0, sBc + 8192 + woff);
    gll16(Bb + 3 * rK + k0, sBc + 12288 + woff);
    __syncthreads();  // drains vmcnt -> LDS tile visible
    shortx8 af[4], bfr[8];
#pragma unroll
    for (int i = 0; i < 4; i++) af[i] = *(const shortx8*)&sA[wm * 64 + i * 16 + frow][fks];
#pragma unroll
    for (int j = 0; j < 8; j++) bfr[j] = *(const shortx8*)&sB[wn * 128 + j * 16 + frow][fks];
#pragma unroll
    for (int i = 0; i < 4; i++)
#pragma unroll
      for (int j = 0; j < 8; j++)
        acc[i][j] = MFMA16(af[i], bfr[j], acc[i][j]);
  }

  const int row0 = bm * 128 + wm * 64 + ((lane >> 4) << 2);
  const int e = lane & 15;
#pragma unroll
  for (int j = 0; j < 8; j++) {
    const int gc = bn * 256 + wn * 128 + j * 16 + e;
    if (EPI == 4) {
      const int sel = gc >> 10, lc = gc & 1023;
      const float* bptr = (sel == 0) ? bias0 : (sel == 1) ? bias1 : bias2;
      bf16* ob = (bf16*)((sel == 0) ? out0 : (sel == 1) ? out1 : out2);
      const float bj = bptr[lc];
#pragma unroll
      for (int i = 0; i < 4; i++) {
#pragma unroll
        for (int r = 0; r < 4; r++) {
          const int row = row0 + i * 16 + r;
          float v = acc[i][j][r] + bj;
          if (sel < 2) v = v > 0.f ? v + 1.f : __expf(v);  // phi = elu+1
          ob[(size_t)row * 1024 + lc] = __float2bfloat16(v);
        }
      }
    } else {
      const float bj = bias0[gc];
#pragma unroll
      for (int i = 0; i < 4; i++) {
#pragma unroll
        for (int r = 0; r < 4; r++) {
          const int row = row0 + i * 16 + r;
          const size_t o = (size_t)row * M + gc;
          float v = acc[i][j][r] + bj;
          if (EPI == 1) {
            ((bf16*)out0)[o] = __float2bfloat16(v);
          } else if (EPI == 2) {
            ((bf16*)out0)[o] = __float2bfloat16(fmaxf(v, 0.f));
          } else {
            ((float*)out0)[o] = v + res[o];
          }
        }
      }
    }
  }
}

// ---------------------------------------------------------------------------
// context via MFMA: ctx[bh,d,e] = sum_s phiK[s,b,h*64+d] * V[s,b,h*64+e]
//                   ksum[bh,d]  = sum_s phiK[s,b,h*64+d]  (ones-B MFMA)
// ---------------------------------------------------------------------------
__global__ __launch_bounds__(256) void ctx_mfma(const bf16* __restrict__ phiK,
                                                const bf16* __restrict__ V,
                                                float* __restrict__ ctx,
                                                float* __restrict__ ksum) {
  __shared__ __align__(16) short sKT[64][72];  // [d][s], stride 144 B
  __shared__ __align__(16) short sVT[64][72];  // [e][s]
  const int bh = blockIdx.x, b = bh >> 4, h = bh & 15;
  const int t = threadIdx.x, lane = t & 63, wave = t >> 6;
  const int s_l = t >> 2;          // 0..63
  const int c0 = (t & 3) << 4;     // 0,16,32,48
  const int frow = lane & 15, fk = (lane >> 4) << 3;
  const shortx8 ones = (shortx8)(short)0x3F80;  // bf16 1.0 splat
  floatx4 acc[4] = {};
  floatx4 accK = {};

  const int sbeg = blockIdx.y * 512;
  for (int sub = 0; sub < 8; sub++) {
    const size_t g = ((size_t)(sbeg + sub * 64 + s_l) * 4 + b) * 1024 + h * 64 + c0;
    shortx8 kv0 = *(const shortx8*)(phiK + g);
    shortx8 kv1 = *(const shortx8*)(phiK + g + 8);
    shortx8 vv0 = *(const shortx8*)(V + g);
    shortx8 vv1 = *(const shortx8*)(V + g + 8);
    __syncthreads();  // previous subtile consumed
#pragma unroll
    for (int j = 0; j < 8; j++) {
      sKT[c0 + j][s_l] = kv0[j];
      sKT[c0 + 8 + j][s_l] = kv1[j];
      sVT[c0 + j][s_l] = vv0[j];
      sVT[c0 + 8 + j][s_l] = vv1[j];
    }
    __syncthreads();
#pragma unroll
    for (int ks = 0; ks < 2; ks++) {
      shortx8 af = *(const shortx8*)&sKT[wave * 16 + frow][ks * 32 + fk];
      accK = MFMA16(af, ones, accK);
#pragma unroll
      for (int j = 0; j < 4; j++) {
        shortx8 bfr = *(const shortx8*)&sVT[j * 16 + frow][ks * 32 + fk];
        acc[j] = MFMA16(af, bfr, acc[j]);
      }
    }
  }

  float* cdst = ctx + (size_t)bh * 4096;
  const int dr0 = wave * 16 + ((lane >> 4) << 2);  // C-layout row base -> d
  const int e = lane & 15;                         // C-layout col -> e offset
#pragma unroll
  for (int j = 0; j < 4; j++)
#pragma unroll
    for (int r = 0; r < 4; r++)
      atomicAdd(cdst + (size_t)(dr0 + r) * 64 + j * 16 + e, acc[j][r]);
  if (e == 0) {
#pragma unroll
    for (int r = 0; r < 4; r++) atomicAdd(ksum + bh * 64 + dr0 + r, accK[r]);
  }
}

// ---------------------------------------------------------------------------
// apply: out[s,b,h*64+e] = (sum_d phiQ[s,d]*ctx[d,e]) / (sum_d phiQ[s,d]*ksum[d] + eps)
// ---------------------------------------------------------------------------
__global__ __launch_bounds__(256) void attn_mfma(const bf16* __restrict__ phiQ,
                                                 const float* __restrict__ ctx,
                                                 const float* __restrict__ ksum,
                                                 bf16* __restrict__ attn) {
  __shared__ __align__(16) bf16 sctxT[64][72];  // [e][d]
  __shared__ __align__(16) bf16 sks[64];
  const int bh = blockIdx.x, b = bh >> 4, h = bh & 15;
  const int t = threadIdx.x, lane = t & 63, wave = t >> 6;
  const float* cbase = ctx + (size_t)bh * 4096;
  for (int idx = t; idx < 4096; idx += 256) {
    int d = idx >> 6, e = idx & 63;
    sctxT[e][d] = __float2bfloat16(cbase[idx]);
  }
  if (t < 64) sks[t] = __float2bfloat16(ksum[bh * 64 + t]);
  __syncthreads();

  const int s0 = blockIdx.y * 128 + wave * 32;
  const int frow = lane & 15, fk = (lane >> 4) << 3;
  shortx8 bfr[2][4], kfr[2];
#pragma unroll
  for (int ks = 0; ks < 2; ks++) {
#pragma unroll
    for (int j = 0; j < 4; j++) bfr[ks][j] = *(const shortx8*)&sctxT[j * 16 + frow][ks * 32 + fk];
    kfr[ks] = *(const shortx8*)&sks[ks * 32 + fk];
  }
  floatx4 acc[2][4] = {};
  floatx4 accd[2] = {};
#pragma unroll
  for (int i = 0; i < 2; i++) {
#pragma unroll
    for (int ks = 0; ks < 2; ks++) {
      const int srow = s0 + i * 16 + frow;
      const bf16* ap = phiQ + ((size_t)srow * 4 + b) * 1024 + h * 64 + ks * 32 + fk;
      shortx8 af = *(const shortx8*)ap;
#pragma unroll
      for (int j = 0; j < 4; j++) acc[i][j] = MFMA16(af, bfr[ks][j], acc[i][j]);
      accd[i] = MFMA16(af, kfr[ks], accd[i]);
    }
  }
#pragma unroll
  for (int i = 0; i < 2; i++) {
#pragma unroll
    for (int r = 0; r < 4; r++) {
      const int srow = s0 + i * 16 + ((lane >> 4) << 2) + r;
      const float den = accd[i][r] + 1e-6f;
#pragma unroll
      for (int j = 0; j < 4; j++) {
        const int e = j * 16 + (lane & 15);
        attn[((size_t)srow * 4 + b) * 1024 + h * 64 + e] = __float2bfloat16(acc[i][j][r] / den);
      }
    }
  }
}

// ---------------------------------------------------------------------------
// layernorm over D=1024: block per row, 256 threads x float4.
// ---------------------------------------------------------------------------
__global__ __launch_bounds__(256) void ln_kernel(const float* __restrict__ x,
                                                 const float* __restrict__ g,
                                                 const float* __restrict__ be,
                                                 float* __restrict__ outf,
                                                 bf16* __restrict__ outb) {
  const int row = blockIdx.x, t = threadIdx.x;
  const float4 v = ((const float4*)(x + (size_t)row * 1024))[t];
  float s = v.x + v.y + v.z + v.w;
  float q = v.x * v.x + v.y * v.y + v.z * v.z + v.w * v.w;
#pragma unroll
  for (int off = 32; off; off >>= 1) {
    s += __shfl_xor(s, off);
    q += __shfl_xor(q, off);
  }
  __shared__ float ss[4], sq[4];
  const int wave = t >> 6;
  if ((t & 63) == 0) { ss[wave] = s; sq[wave] = q; }
  __syncthreads();
  s = ss[0] + ss[1] + ss[2] + ss[3];
  q = sq[0] + sq[1] + sq[2] + sq[3];
  const float mu = s * (1.f / 1024.f);
  const float var = q * (1.f / 1024.f) - mu * mu;
  const float rstd = rsqrtf(var + 1e-5f);
  const float4 gv = ((const float4*)g)[t];
  const float4 bv = ((const float4*)be)[t];
  float4 y;
  y.x = (v.x - mu) * rstd * gv.x + bv.x;
  y.y = (v.y - mu) * rstd * gv.y + bv.y;
  y.z = (v.z - mu) * rstd * gv.z + bv.z;
  y.w = (v.w - mu) * rstd * gv.w + bv.w;
  ((float4*)(outf + (size_t)row * 1024))[t] = y;
  if (outb != nullptr) {
    bf16 h0 = __float2bfloat16(y.x), h1 = __float2bfloat16(y.y);
    bf16 h2 = __float2bfloat16(y.z), h3 = __float2bfloat16(y.w);
    ushort4 u;
    u.x = __builtin_bit_cast(unsigned short, h0);
    u.y = __builtin_bit_cast(unsigned short, h1);
    u.z = __builtin_bit_cast(unsigned short, h2);
    u.w = __builtin_bit_cast(unsigned short, h3);
    ((ushort4*)(outb + (size_t)row * 1024))[t] = u;
  }
}

// ---------------------------------------------------------------------------
extern "C" void kernel_launch(void* const* d_in, const int* in_sizes, int n_in,
                              void* d_out, int out_size, void* d_ws, size_t ws_size,
                              hipStream_t stream) {
  const float* src = (const float*)d_in[0];
  const float* Wq = (const float*)d_in[1];
  const float* bq = (const float*)d_in[2];
  const float* Wk = (const float*)d_in[3];
  const float* bk = (const float*)d_in[4];
  const float* Wv = (const float*)d_in[5];
  const float* bv = (const float*)d_in[6];
  const float* Wo = (const float*)d_in[7];
  const float* bo = (const float*)d_in[8];
  const float* W1 = (const float*)d_in[9];
  const float* b1 = (const float*)d_in[10];
  const float* W2 = (const float*)d_in[11];
  const float* b2 = (const float*)d_in[12];
  const float* g1 = (const float*)d_in[13];
  const float* be1 = (const float*)d_in[14];
  const float* g2 = (const float*)d_in[15];
  const float* be2 = (const float*)d_in[16];

  const size_t MB = 1024 * 1024;
  char* w = (char*)d_ws;
  bf16* src_bf = (bf16*)(w + 0);          // 32 MB, dead after QKV GEMM
  float* x1 = (float*)(w + 0);            // 64 MB (src + attn@Wo), dead after LN1
  float* x2 = (float*)(w + 0);            // 64 MB (out1 + ffn), dead after LN2
  bf16* phiQ = (bf16*)(w + 64 * MB);      // 32 MB
  bf16* phiK = (bf16*)(w + 96 * MB);      // 32 MB, dead after ctx
  bf16* attn = (bf16*)(w + 96 * MB);      // 32 MB
  bf16* Vb = (bf16*)(w + 128 * MB);       // 32 MB, dead after ctx
  bf16* out1b = (bf16*)(w + 128 * MB);    // 32 MB
  float* out1f = (float*)(w + 160 * MB);  // 64 MB
  bf16* Wq_b = (bf16*)(w + 224 * MB);     // Wq/Wk/Wv contiguous -> fused QKV GEMM
  bf16* Wk_b = (bf16*)(w + 226 * MB);
  bf16* Wv_b = (bf16*)(w + 228 * MB);
  bf16* Wo_b = (bf16*)(w + 230 * MB);
  bf16* W1_b = (bf16*)(w + 232 * MB);
  bf16* W2_b = (bf16*)(w + 236 * MB);
  float* ctx = (float*)(w + 240 * MB);    // 64*64*64 fp32 = 1 MB
  float* ksum = (float*)(w + 241 * MB);   // 4096 fp32
  bf16* H1 = (bf16*)d_out;                // 16384x2048 bf16 = 64 MB scratch in d_out
  float* outf = (float*)d_out;

  const dim3 blk(256);
  f2b_all<<<24576, blk, 0, stream>>>(src, Wq, Wk, Wv, Wo, W1, W2, src_bf, Wq_b,
                                     Wk_b, Wv_b, Wo_b, W1_b, W2_b);
  hipMemsetAsync(ctx, 0, (64 * 64 * 64 + 64 * 64) * sizeof(float), stream);

  // fused QKV: A=src_bf, B=[Wq;Wk;Wv] (3072 rows), epilogue splits 3 outputs
  gemm_nt<4><<<dim3(128, 12), blk, 0, stream>>>(src_bf, Wq_b, bq, bk, bv, nullptr,
                                                phiQ, phiK, Vb, 3072, 1024);
  ctx_mfma<<<dim3(64, 8), blk, 0, stream>>>(phiK, Vb, ctx, ksum);
  attn_mfma<<<dim3(64, 32), blk, 0, stream>>>(phiQ, ctx, ksum, attn);
  gemm_nt<3><<<dim3(128, 4), blk, 0, stream>>>(attn, Wo_b, bo, nullptr, nullptr,
                                               src, x1, nullptr, nullptr, 1024, 1024);
  ln_kernel<<<16384, blk, 0, stream>>>(x1, g1, be1, out1f, out1b);
  gemm_nt<2><<<dim3(128, 8), blk, 0, stream>>>(out1b, W1_b, b1, nullptr, nullptr,
                                               nullptr, H1, nullptr, nullptr, 2048, 1024);
  gemm_nt<3><<<dim3(128, 4), blk, 0, stream>>>(H1, W2_b, b2, nullptr, nullptr,
                                               out1f, x2, nullptr, nullptr, 1024, 2048);
  ln_kernel<<<16384, blk, 0, stream>>>(x2, g2, be2, outf, nullptr);
}

// Round 6
// 559.750 us; speedup vs baseline: 1.2555x; 1.2555x over previous
//
#include <hip/hip_runtime.h>
#include <hip/hip_bf16.h>

typedef __hip_bfloat16 bf16;
typedef __attribute__((ext_vector_type(4))) float floatx4;
typedef __attribute__((ext_vector_type(8))) short shortx8;

#define MFMA16(a, b, c) __builtin_amdgcn_mfma_f32_16x16x32_bf16(a, b, c, 0, 0, 0)

__device__ __forceinline__ void gll16(const bf16* g, void* l) {
  __builtin_amdgcn_global_load_lds((const __attribute__((address_space(1))) unsigned int*)g,
                                   (__attribute__((address_space(3))) unsigned int*)l,
                                   16, 0, 0);
}

__device__ __forceinline__ float b2f(short s) {
  return __bfloat162float(__builtin_bit_cast(bf16, (unsigned short)s));
}
__device__ __forceinline__ short f2b(float f) {
  return __builtin_bit_cast(short, __float2bfloat16(f));
}

// ---------------------------------------------------------------------------
// fused fp32 -> bf16 converts: src (16384 blks) + 6 weights (8192 blks)
// ---------------------------------------------------------------------------
__global__ __launch_bounds__(256) void f2b_all(
    const float* __restrict__ src, const float* __restrict__ Wq,
    const float* __restrict__ Wk, const float* __restrict__ Wv,
    const float* __restrict__ Wo, const float* __restrict__ W1,
    const float* __restrict__ W2, bf16* __restrict__ src_bf,
    bf16* __restrict__ Wq_b, bf16* __restrict__ Wk_b, bf16* __restrict__ Wv_b,
    bf16* __restrict__ Wo_b, bf16* __restrict__ W1_b, bf16* __restrict__ W2_b) {
  const int blk = blockIdx.x;
  const float* in;
  bf16* out;
  int off;
  if (blk < 16384)      { in = src; out = src_bf; off = blk; }
  else if (blk < 17408) { in = Wq; out = Wq_b; off = blk - 16384; }
  else if (blk < 18432) { in = Wk; out = Wk_b; off = blk - 17408; }
  else if (blk < 19456) { in = Wv; out = Wv_b; off = blk - 18432; }
  else if (blk < 20480) { in = Wo; out = Wo_b; off = blk - 19456; }
  else if (blk < 22528) { in = W1; out = W1_b; off = blk - 20480; }
  else                  { in = W2; out = W2_b; off = blk - 22528; }
  const int i = (off * 256 + threadIdx.x) * 4;
  float4 v = *(const float4*)(in + i);
  ushort4 u;
  u.x = (unsigned short)f2b(v.x);
  u.y = (unsigned short)f2b(v.y);
  u.z = (unsigned short)f2b(v.z);
  u.w = (unsigned short)f2b(v.w);
  *(ushort4*)(out + i) = u;
}

// ---------------------------------------------------------------------------
// NT GEMM: C[n,m] = A[n,:] . W[m,:]  (A [N,K] bf16, W [M,K] bf16, K-major)
// Tile 128x256, BK=32, 24 KB LDS K-loop (round-5 structure, model-validated:
// dispatch time ~= staged bytes / ~8 TB/s).
// NEW: LDS-staged coalesced epilogue. Round-5 PMC showed 2.46x WRITE
// amplification (236 MB vs 96 ideal on QKV) from scalar 2-B C-stores in
// MFMA C-layout. Fragments now go to LDS (aliasing dead sA/sB), then
// row-linear 16-B stores -> full 64-B lines. Residual reads coalesced too.
// EPI: 1 id->bf16 ; 2 relu->bf16 ; 3 +res(fp32)->bf16 ; 4 fused QKV
//      (block-uniform sel: phi->phiQ/phiK, id->V) ; 5 +res(bf16)->bf16
// ---------------------------------------------------------------------------
template <int EPI>
__global__ __launch_bounds__(256, 2) void gemm_nt(
    const bf16* __restrict__ A, const bf16* __restrict__ Bw,
    const float* __restrict__ bias0, const float* __restrict__ bias1,
    const float* __restrict__ bias2, const float* __restrict__ resf,
    const bf16* __restrict__ resb, void* __restrict__ out0,
    void* __restrict__ out1, void* __restrict__ out2, const int M,
    const int K) {
  __shared__ __align__(16) char smem[24576];
  bf16* sA = (bf16*)smem;          // [128][32]
  bf16* sB = (bf16*)(smem + 8192); // [256][32]
  bf16* cep = (bf16*)smem;         // epilogue alias: [2][16][268] = 17152 B
#define CEP(gg, rr, cc) cep[(((gg)*16 + (rr)) * 268) + (cc)]
  const int tid = threadIdx.x;
  const int lane = tid & 63, wave = tid >> 6;
  const int wm = wave & 1, wn = wave >> 1;
  const int bm = blockIdx.x, bn = blockIdx.y;
  floatx4 acc[4][8] = {};
  const int srow = tid >> 2;
  const int schunk = (tid & 3) ^ ((srow >> 1) & 3);
  const bf16* Ab = A + (size_t)(bm * 128 + srow) * K + schunk * 8;
  const bf16* Bb = Bw + (size_t)(bn * 256 + srow) * K + schunk * 8;
  const int woff = wave * 1024;
  const int frow = lane & 15;
  const int fks = (((lane >> 4) ^ ((frow >> 1) & 3))) << 3;
  const size_t rK = (size_t)64 * K;

  for (int k0 = 0; k0 < K; k0 += 32) {
    __syncthreads();
    gll16(Ab + k0, smem + woff);
    gll16(Ab + rK + k0, smem + 4096 + woff);
    gll16(Bb + k0, smem + 8192 + woff);
    gll16(Bb + rK + k0, smem + 12288 + woff);
    gll16(Bb + 2 * rK + k0, smem + 16384 + woff);
    gll16(Bb + 3 * rK + k0, smem + 20480 + woff);
    __syncthreads();
    shortx8 af[4], bfr[8];
#pragma unroll
    for (int i = 0; i < 4; i++)
      af[i] = *(const shortx8*)&sA[(wm * 64 + i * 16 + frow) * 32 + fks];
#pragma unroll
    for (int j = 0; j < 8; j++)
      bfr[j] = *(const shortx8*)&sB[(wn * 128 + j * 16 + frow) * 32 + fks];
#pragma unroll
    for (int i = 0; i < 4; i++)
#pragma unroll
      for (int j = 0; j < 8; j++)
        acc[i][j] = MFMA16(af[i], bfr[j], acc[i][j]);
  }

  // ---- epilogue: C-layout fragments -> LDS -> coalesced 16-B stores ----
  // block-uniform output selection (EPI=4: 256|1024 so a bn tile never
  // crosses a Q/K/V boundary)
  const float* bptr = bias0;
  bf16* ob = (bf16*)out0;
  int colbase = bn * 256;
  int phi = 0;
  if (EPI == 4) {
    const int sel = bn >> 2;
    bptr = (sel == 0) ? bias0 : (sel == 1) ? bias1 : bias2;
    ob = (bf16*)((sel == 0) ? out0 : (sel == 1) ? out1 : out2);
    colbase = (bn & 3) * 256;
    phi = (sel < 2);
  }
  const int e = lane & 15, q4 = (lane >> 4) << 2;
  float bj[8];
#pragma unroll
  for (int j = 0; j < 8; j++) bj[j] = bptr[colbase + wn * 128 + j * 16 + e];

  const int g = tid >> 7;            // write-phase row group (0..1)
  const int rowl = (tid >> 3) & 15;  // write-phase local row
  const int cch = (tid & 7) * 8;     // write-phase col chunk

#pragma unroll
  for (int i = 0; i < 4; i++) {
    __syncthreads();  // previous phase (K-loop or prior writes) done with LDS
#pragma unroll
    for (int j = 0; j < 8; j++) {
#pragma unroll
      for (int r = 0; r < 4; r++) {
        float v = acc[i][j][r] + bj[j];
        if (EPI == 4 && phi) v = v > 0.f ? v + 1.f : __expf(v);
        if (EPI == 2) v = fmaxf(v, 0.f);
        CEP(wm, q4 + r, wn * 128 + j * 16 + e) = __builtin_bit_cast(bf16, f2b(v));
      }
    }
    __syncthreads();
    const int grow = bm * 128 + g * 64 + i * 16 + rowl;
#pragma unroll
    for (int c = 0; c < 4; c++) {
      const int col = cch + c * 64;
      shortx8 v = *(const shortx8*)&CEP(g, rowl, col);
      if (EPI == 3) {
        const float* rp = resf + (size_t)grow * M + colbase + col;
        float4 r0 = *(const float4*)rp;
        float4 r1 = *(const float4*)(rp + 4);
        v[0] = f2b(b2f(v[0]) + r0.x); v[1] = f2b(b2f(v[1]) + r0.y);
        v[2] = f2b(b2f(v[2]) + r0.z); v[3] = f2b(b2f(v[3]) + r0.w);
        v[4] = f2b(b2f(v[4]) + r1.x); v[5] = f2b(b2f(v[5]) + r1.y);
        v[6] = f2b(b2f(v[6]) + r1.z); v[7] = f2b(b2f(v[7]) + r1.w);
      } else if (EPI == 5) {
        shortx8 rv = *(const shortx8*)(resb + (size_t)grow * M + colbase + col);
#pragma unroll
        for (int k = 0; k < 8; k++) v[k] = f2b(b2f(v[k]) + b2f(rv[k]));
      }
      *(shortx8*)(ob + (size_t)grow * M + colbase + col) = v;
    }
  }
#undef CEP
}

// ---------------------------------------------------------------------------
// context via MFMA: ctx[bh,d,e] = sum_s phiK[s,b,h*64+d] * V[s,b,h*64+e]
//                   ksum[bh,d]  = sum_s phiK[s,b,h*64+d]  (ones-B MFMA)
// ---------------------------------------------------------------------------
__global__ __launch_bounds__(256) void ctx_mfma(const bf16* __restrict__ phiK,
                                                const bf16* __restrict__ V,
                                                float* __restrict__ ctx,
                                                float* __restrict__ ksum) {
  __shared__ __align__(16) short sKT[64][72];
  __shared__ __align__(16) short sVT[64][72];
  const int bh = blockIdx.x, b = bh >> 4, h = bh & 15;
  const int t = threadIdx.x, lane = t & 63, wave = t >> 6;
  const int s_l = t >> 2;
  const int c0 = (t & 3) << 4;
  const int frow = lane & 15, fk = (lane >> 4) << 3;
  const shortx8 ones = (shortx8)(short)0x3F80;
  floatx4 acc[4] = {};
  floatx4 accK = {};

  const int sbeg = blockIdx.y * 512;
  for (int sub = 0; sub < 8; sub++) {
    const size_t g = ((size_t)(sbeg + sub * 64 + s_l) * 4 + b) * 1024 + h * 64 + c0;
    shortx8 kv0 = *(const shortx8*)(phiK + g);
    shortx8 kv1 = *(const shortx8*)(phiK + g + 8);
    shortx8 vv0 = *(const shortx8*)(V + g);
    shortx8 vv1 = *(const shortx8*)(V + g + 8);
    __syncthreads();
#pragma unroll
    for (int j = 0; j < 8; j++) {
      sKT[c0 + j][s_l] = kv0[j];
      sKT[c0 + 8 + j][s_l] = kv1[j];
      sVT[c0 + j][s_l] = vv0[j];
      sVT[c0 + 8 + j][s_l] = vv1[j];
    }
    __syncthreads();
#pragma unroll
    for (int ks = 0; ks < 2; ks++) {
      shortx8 af = *(const shortx8*)&sKT[wave * 16 + frow][ks * 32 + fk];
      accK = MFMA16(af, ones, accK);
#pragma unroll
      for (int j = 0; j < 4; j++) {
        shortx8 bfr = *(const shortx8*)&sVT[j * 16 + frow][ks * 32 + fk];
        acc[j] = MFMA16(af, bfr, acc[j]);
      }
    }
  }

  float* cdst = ctx + (size_t)bh * 4096;
  const int dr0 = wave * 16 + ((lane >> 4) << 2);
  const int e = lane & 15;
#pragma unroll
  for (int j = 0; j < 4; j++)
#pragma unroll
    for (int r = 0; r < 4; r++)
      atomicAdd(cdst + (size_t)(dr0 + r) * 64 + j * 16 + e, acc[j][r]);
  if (e == 0) {
#pragma unroll
    for (int r = 0; r < 4; r++) atomicAdd(ksum + bh * 64 + dr0 + r, accK[r]);
  }
}

// ---------------------------------------------------------------------------
// apply: out[s,b,h*64+e] = (phiQ[s,:].ctx[:,e]) / (phiQ[s,:].ksum + eps)
// ---------------------------------------------------------------------------
__global__ __launch_bounds__(256) void attn_mfma(const bf16* __restrict__ phiQ,
                                                 const float* __restrict__ ctx,
                                                 const float* __restrict__ ksum,
                                                 bf16* __restrict__ attn) {
  __shared__ __align__(16) bf16 sctxT[64][72];
  __shared__ __align__(16) bf16 sks[64];
  const int bh = blockIdx.x, b = bh >> 4, h = bh & 15;
  const int t = threadIdx.x, lane = t & 63, wave = t >> 6;
  const float* cbase = ctx + (size_t)bh * 4096;
  for (int idx = t; idx < 4096; idx += 256) {
    int d = idx >> 6, e = idx & 63;
    sctxT[e][d] = __float2bfloat16(cbase[idx]);
  }
  if (t < 64) sks[t] = __float2bfloat16(ksum[bh * 64 + t]);
  __syncthreads();

  const int s0 = blockIdx.y * 128 + wave * 32;
  const int frow = lane & 15, fk = (lane >> 4) << 3;
  shortx8 bfr[2][4], kfr[2];
#pragma unroll
  for (int ks = 0; ks < 2; ks++) {
#pragma unroll
    for (int j = 0; j < 4; j++) bfr[ks][j] = *(const shortx8*)&sctxT[j * 16 + frow][ks * 32 + fk];
    kfr[ks] = *(const shortx8*)&sks[ks * 32 + fk];
  }
  floatx4 acc[2][4] = {};
  floatx4 accd[2] = {};
#pragma unroll
  for (int i = 0; i < 2; i++) {
#pragma unroll
    for (int ks = 0; ks < 2; ks++) {
      const int srow = s0 + i * 16 + frow;
      const bf16* ap = phiQ + ((size_t)srow * 4 + b) * 1024 + h * 64 + ks * 32 + fk;
      shortx8 af = *(const shortx8*)ap;
#pragma unroll
      for (int j = 0; j < 4; j++) acc[i][j] = MFMA16(af, bfr[ks][j], acc[i][j]);
      accd[i] = MFMA16(af, kfr[ks], accd[i]);
    }
  }
#pragma unroll
  for (int i = 0; i < 2; i++) {
#pragma unroll
    for (int r = 0; r < 4; r++) {
      const int srow = s0 + i * 16 + ((lane >> 4) << 2) + r;
      const float den = accd[i][r] + 1e-6f;
#pragma unroll
      for (int j = 0; j < 4; j++) {
        const int e = j * 16 + (lane & 15);
        attn[((size_t)srow * 4 + b) * 1024 + h * 64 + e] = __float2bfloat16(acc[i][j][r] / den);
      }
    }
  }
}

// ---------------------------------------------------------------------------
// layernorm over D=1024, bf16 input: block per row, 256 threads x 4.
// writes bf16 (outb) or fp32 (outf).
// ---------------------------------------------------------------------------
__global__ __launch_bounds__(256) void ln_kernel(const bf16* __restrict__ x,
                                                 const float* __restrict__ g,
                                                 const float* __restrict__ be,
                                                 bf16* __restrict__ outb,
                                                 float* __restrict__ outf) {
  const int row = blockIdx.x, t = threadIdx.x;
  const ushort4 u = ((const ushort4*)(x + (size_t)row * 1024))[t];
  float v0 = b2f((short)u.x), v1 = b2f((short)u.y);
  float v2 = b2f((short)u.z), v3 = b2f((short)u.w);
  float s = v0 + v1 + v2 + v3;
  float q = v0 * v0 + v1 * v1 + v2 * v2 + v3 * v3;
#pragma unroll
  for (int off = 32; off; off >>= 1) {
    s += __shfl_xor(s, off);
    q += __shfl_xor(q, off);
  }
  __shared__ float ss[4], sq[4];
  const int wave = t >> 6;
  if ((t & 63) == 0) { ss[wave] = s; sq[wave] = q; }
  __syncthreads();
  s = ss[0] + ss[1] + ss[2] + ss[3];
  q = sq[0] + sq[1] + sq[2] + sq[3];
  const float mu = s * (1.f / 1024.f);
  const float var = q * (1.f / 1024.f) - mu * mu;
  const float rstd = rsqrtf(var + 1e-5f);
  const float4 gv = ((const float4*)g)[t];
  const float4 bv = ((const float4*)be)[t];
  float y0 = (v0 - mu) * rstd * gv.x + bv.x;
  float y1 = (v1 - mu) * rstd * gv.y + bv.y;
  float y2 = (v2 - mu) * rstd * gv.z + bv.z;
  float y3 = (v3 - mu) * rstd * gv.w + bv.w;
  if (outb != nullptr) {
    ushort4 o;
    o.x = (unsigned short)f2b(y0); o.y = (unsigned short)f2b(y1);
    o.z = (unsigned short)f2b(y2); o.w = (unsigned short)f2b(y3);
    ((ushort4*)(outb + (size_t)row * 1024))[t] = o;
  } else {
    float4 o = {y0, y1, y2, y3};
    ((float4*)(outf + (size_t)row * 1024))[t] = o;
  }
}

// ---------------------------------------------------------------------------
extern "C" void kernel_launch(void* const* d_in, const int* in_sizes, int n_in,
                              void* d_out, int out_size, void* d_ws, size_t ws_size,
                              hipStream_t stream) {
  const float* src = (const float*)d_in[0];
  const float* Wq = (const float*)d_in[1];
  const float* bq = (const float*)d_in[2];
  const float* Wk = (const float*)d_in[3];
  const float* bk = (const float*)d_in[4];
  const float* Wv = (const float*)d_in[5];
  const float* bv = (const float*)d_in[6];
  const float* Wo = (const float*)d_in[7];
  const float* bo = (const float*)d_in[8];
  const float* W1 = (const float*)d_in[9];
  const float* b1 = (const float*)d_in[10];
  const float* W2 = (const float*)d_in[11];
  const float* b2 = (const float*)d_in[12];
  const float* g1 = (const float*)d_in[13];
  const float* be1 = (const float*)d_in[14];
  const float* g2 = (const float*)d_in[15];
  const float* be2 = (const float*)d_in[16];

  const size_t MB = 1024 * 1024;
  char* w = (char*)d_ws;
  bf16* src_bf = (bf16*)(w + 0);          // 32 MB, dead after QKV GEMM
  bf16* x1b = (bf16*)(w + 0);             // 32 MB (src + attn@Wo, bf16), after QKV
  bf16* phiQ = (bf16*)(w + 64 * MB);      // 32 MB
  bf16* phiK = (bf16*)(w + 96 * MB);      // 32 MB, dead after ctx
  bf16* attn = (bf16*)(w + 96 * MB);      // 32 MB
  bf16* Vb = (bf16*)(w + 128 * MB);       // 32 MB, dead after ctx
  bf16* out1b = (bf16*)(w + 128 * MB);    // 32 MB (LN1 out, FFN2 residual)
  bf16* x2b = (bf16*)(w + 160 * MB);      // 32 MB (out1 + ffn, bf16)
  bf16* Wq_b = (bf16*)(w + 224 * MB);     // Wq/Wk/Wv contiguous
  bf16* Wk_b = (bf16*)(w + 226 * MB);
  bf16* Wv_b = (bf16*)(w + 228 * MB);
  bf16* Wo_b = (bf16*)(w + 230 * MB);
  bf16* W1_b = (bf16*)(w + 232 * MB);
  bf16* W2_b = (bf16*)(w + 236 * MB);
  float* ctx = (float*)(w + 240 * MB);
  float* ksum = (float*)(w + 241 * MB);
  bf16* H1 = (bf16*)d_out;                // 16384x2048 bf16 scratch in d_out
  float* outf = (float*)d_out;

  const dim3 blk(256);
  f2b_all<<<24576, blk, 0, stream>>>(src, Wq, Wk, Wv, Wo, W1, W2, src_bf, Wq_b,
                                     Wk_b, Wv_b, Wo_b, W1_b, W2_b);
  hipMemsetAsync(ctx, 0, (64 * 64 * 64 + 64 * 64) * sizeof(float), stream);

  // fused QKV: B = [Wq;Wk;Wv] (3072 rows), sel block-uniform per bn tile
  gemm_nt<4><<<dim3(128, 12), blk, 0, stream>>>(
      src_bf, Wq_b, bq, bk, bv, nullptr, nullptr, phiQ, phiK, Vb, 1024, 1024);
  ctx_mfma<<<dim3(64, 8), blk, 0, stream>>>(phiK, Vb, ctx, ksum);
  attn_mfma<<<dim3(64, 32), blk, 0, stream>>>(phiQ, ctx, ksum, attn);
  // out projection + residual(src fp32) -> bf16
  gemm_nt<3><<<dim3(128, 4), blk, 0, stream>>>(
      attn, Wo_b, bo, nullptr, nullptr, src, nullptr, x1b, nullptr, nullptr, 1024, 1024);
  ln_kernel<<<16384, blk, 0, stream>>>(x1b, g1, be1, out1b, nullptr);
  // FFN
  gemm_nt<2><<<dim3(128, 8), blk, 0, stream>>>(
      out1b, W1_b, b1, nullptr, nullptr, nullptr, nullptr, H1, nullptr, nullptr, 2048, 1024);
  gemm_nt<5><<<dim3(128, 4), blk, 0, stream>>>(
      H1, W2_b, b2, nullptr, nullptr, nullptr, out1b, x2b, nullptr, nullptr, 1024, 2048);
  ln_kernel<<<16384, blk, 0, stream>>>(x2b, g2, be2, nullptr, outf);
}